// Round 3
// baseline (4399.953 us; speedup 1.0000x reference)
//
#include <hip/hip_runtime.h>
#include <hip/hip_bf16.h>
#include <math.h>

// NeighborGatedAttention, bf16-MFMA, 16-wave version.
// L=2, B=8192, NNEI=128, EMB=HID=128. One block (1024 thr = 16 waves) per b,
// 4 waves/SIMD. Wave pair (wh, wp): wh = n-group, wp splits phase work:
//   qkv: j-tiles 12/12 | VW,PV: e-tiles 4/4 | S: m-tiles 4/4 (softmax sum and
//   LN mean/var combined cross-wave via LDS partials).
// All GEMMs v_mfma_f32_16x16x32_bf16; l2-norms from fp32 accs folded into
// S/P epilogues; softmax/LN fp32.

typedef __attribute__((ext_vector_type(8))) short bf16x8; // 8 bf16 = 4 VGPR
typedef __attribute__((ext_vector_type(4))) float f32x4;
typedef unsigned short ushort_t;

constexpr float F_SHIFT   = 20.0f;
constexpr float F_SCALING = 0.08838834764831845f; // 128^-0.5
constexpr float F_LNEPS   = 1e-5f;

constexpr int ROWP = 136;                 // ushort row pitch (272B)
constexpr int BUF_US = 128 * ROWP;        // 17408 ushorts per buffer
constexpr size_t WTI_ELEMS = 2 * 384 * 128;
constexpr size_t WTO_ELEMS = 2 * 128 * 128;
// floats: pQ,pK0,pK1,pV(512) fA(512) fB(256) SW/MK/RX/RY/RZ(640) sPS(256) sL1(256) sL2(256)
constexpr int NFLOATS = 512 + 512 + 256 + 640 + 256 + 256 + 256;  // 2688
constexpr int LDS_BYTES = 3 * BUF_US * 2 + NFLOATS * 4;           // 115200

#define MFMA(a, b, c) __builtin_amdgcn_mfma_f32_16x16x32_bf16(a, b, c, 0, 0, 0)

__device__ __forceinline__ ushort_t f2bf(float f) {
  __hip_bfloat16 h = __float2bfloat16(f);
  return *reinterpret_cast<ushort_t*>(&h);
}
__device__ __forceinline__ ushort4 pack4(float a, float b, float c, float d) {
  return make_ushort4(f2bf(a), f2bf(b), f2bf(c), f2bf(d));
}

// A/B fragment from pre-transposed bf16 weights (WS) or fp32 gather fallback.
template <bool WS>
__device__ __forceinline__ bf16x8 wt_frag(const ushort_t* __restrict__ wt,
                                          const float* __restrict__ W,
                                          int r, int c, int ldW) {
  if constexpr (WS) {
    return *(const bf16x8*)(wt + r * 128 + c);
  } else {
    bf16x8 f;
#pragma unroll
    for (int j = 0; j < 8; ++j) f[j] = (short)f2bf(W[(size_t)(c + j) * ldW + r]);
    return f;
  }
}

__global__ void prep_weights(const float* __restrict__ Win, const float* __restrict__ Wout,
                             ushort_t* __restrict__ wtI, ushort_t* __restrict__ wtO) {
  const int i = blockIdx.x * 256 + threadIdx.x;
  if (i < (int)WTI_ELEMS) {   // wtI[l][h][e] = bf16(Win[l][e][h])
    const int l = i / (384 * 128), r = i % (384 * 128), h = r >> 7, e = r & 127;
    wtI[i] = f2bf(Win[l * (128 * 384) + e * 384 + h]);
  }
  if (i < (int)WTO_ELEMS) {   // wtO[l][e][h] = bf16(Wout[l][h][e])
    const int l = i >> 14, r = i & 16383, e = r >> 7, h = r & 127;
    wtO[i] = f2bf(Wout[(l << 14) + h * 128 + e]);
  }
}

__device__ __forceinline__ void qkv_epi(int ht, const f32x4& acc,
                                        const float* __restrict__ binL,
                                        int n_mine, int lg,
                                        ushort_t* bufQ, ushort_t* bufK, ushort_t* bufV,
                                        float& ssq, float& ssk, float& ssv) {
  const int hb = 16 * (ht & 7) + 4 * lg;
  const float4 bi = *(const float4*)&binL[16 * ht + 4 * lg];
  const float v0 = acc[0] + bi.x, v1 = acc[1] + bi.y, v2 = acc[2] + bi.z, v3 = acc[3] + bi.w;
  const float ssl = v0 * v0 + v1 * v1 + v2 * v2 + v3 * v3;
  ushort_t* dst;
  if (ht < 8)       { ssq += ssl; dst = bufQ; }
  else if (ht < 16) { ssk += ssl; dst = bufK; }
  else              { ssv += ssl; dst = bufV; }
  *(ushort4*)(dst + n_mine * ROWP + hb) = pack4(v0, v1, v2, v3);
}

template <bool WS>
__global__ __launch_bounds__(1024, 4)
void ngatt_mfma(const float* __restrict__ G, const int* __restrict__ nmask,
                const float* __restrict__ r3, const float* __restrict__ swg,
                const float* __restrict__ Win, const float* __restrict__ bin,
                const float* __restrict__ Wout, const float* __restrict__ bout,
                const float* __restrict__ lng, const float* __restrict__ lnb,
                const ushort_t* __restrict__ wtin, const ushort_t* __restrict__ wtout,
                float* __restrict__ xout) {
  extern __shared__ char smem[];
  ushort_t* bufQ = (ushort_t*)smem;            // q, then P
  ushort_t* bufK = bufQ + BUF_US;              // k
  ushort_t* bufV = bufK + BUF_US;              // v, then VW^T
  float* pQ  = (float*)(bufV + BUF_US);        // q norm partial -> 1/|q|
  float* pK0 = pQ  + 128;
  float* pK1 = pK0 + 128;
  float* pV  = pK1 + 128;
  float* fA  = pV  + 128;                      // [128] x4 {invk*SCL, sw, invv, rx}
  float* fB  = fA  + 512;                      // [128] x2 {ry, rz}
  float* sSW = fB  + 256;
  float* sMK = sSW + 128;
  float* sRX = sMK + 128;
  float* sRY = sRX + 128;
  float* sRZ = sRY + 128;
  float* sPS = sRZ + 128;                      // [2][128] softmax partial sums
  float* sL1 = sPS + 256;                      // [2][128] LN sum partials
  float* sL2 = sL1 + 256;                      // [2][128] LN sumsq partials

  const int b = blockIdx.x, t = threadIdx.x;
  const int w = t >> 6, wh = w & 7, wp = w >> 3;
  const int l = t & 63, lc = l & 15, lg = l >> 4;
  const size_t bb = (size_t)b * (128 * 128);
  const int n_mine = 16 * wh + lc;

  if (t < 128) {
    const size_t gi = (size_t)b * 128 + t;
    sSW[t] = swg[gi];
    sMK[t] = nmask[gi] ? 1.0f : 0.0f;
    sRX[t] = r3[gi * 3 + 0]; sRY[t] = r3[gi * 3 + 1]; sRZ[t] = r3[gi * 3 + 2];
  }
  __syncthreads();

  for (int layer = 0; layer < 2; ++layer) {
    const float* xsrc = layer ? (xout + bb) : (G + bb);
    const ushort_t* wtI = wtin + (size_t)layer * 384 * 128;
    const ushort_t* wtO = wtout + (size_t)layer * 128 * 128;
    const float* WinL  = Win  + (size_t)layer * 128 * 384;
    const float* WoutL = Wout + (size_t)layer * 128 * 128;
    const float* binL  = bin  + layer * 384;
    const float* boutL = bout + layer * 128;
    const float* lngL  = lng  + layer * 128;
    const float* lnbL  = lnb  + layer * 128;

    // ---- hoist x B-fragments for column-group wh (both wp same) ----
    bf16x8 xf[4];
    {
      const float* xr = xsrc + (size_t)n_mine * 128 + 8 * lg;
#pragma unroll
      for (int kk = 0; kk < 4; ++kk) {
        const float4 a = *(const float4*)(xr + 32 * kk);
        const float4 c = *(const float4*)(xr + 32 * kk + 4);
        bf16x8 f;
        f[0] = (short)f2bf(a.x); f[1] = (short)f2bf(a.y);
        f[2] = (short)f2bf(a.z); f[3] = (short)f2bf(a.w);
        f[4] = (short)f2bf(c.x); f[5] = (short)f2bf(c.y);
        f[6] = (short)f2bf(c.z); f[7] = (short)f2bf(c.w);
        xf[kk] = f;
      }
    }

    // ---- qkv^T gemm: wave handles 12 of 24 row-tiles (paired, prefetch-1) ----
    float ssq = 0.f, ssk = 0.f, ssv = 0.f;
    {
      const int base = 12 * wp;
      bf16x8 awA[4], awB[4], nwA[4], nwB[4];
#pragma unroll
      for (int kk = 0; kk < 4; ++kk) {
        awA[kk] = wt_frag<WS>(wtI, WinL, 16 * base + lc,       8 * lg + 32 * kk, 384);
        awB[kk] = wt_frag<WS>(wtI, WinL, 16 * (base + 6) + lc, 8 * lg + 32 * kk, 384);
      }
      for (int i = 0; i < 6; ++i) {
        if (i < 5) {
#pragma unroll
          for (int kk = 0; kk < 4; ++kk) {
            nwA[kk] = wt_frag<WS>(wtI, WinL, 16 * (base + i + 1) + lc, 8 * lg + 32 * kk, 384);
            nwB[kk] = wt_frag<WS>(wtI, WinL, 16 * (base + i + 7) + lc, 8 * lg + 32 * kk, 384);
          }
        }
        f32x4 aA = {0, 0, 0, 0}, aB = {0, 0, 0, 0};
#pragma unroll
        for (int kk = 0; kk < 4; ++kk) {
          aA = MFMA(awA[kk], xf[kk], aA);
          aB = MFMA(awB[kk], xf[kk], aB);
        }
        qkv_epi(base + i,     aA, binL, n_mine, lg, bufQ, bufK, bufV, ssq, ssk, ssv);
        qkv_epi(base + i + 6, aB, binL, n_mine, lg, bufQ, bufK, bufV, ssq, ssk, ssv);
#pragma unroll
        for (int kk = 0; kk < 4; ++kk) { awA[kk] = nwA[kk]; awB[kk] = nwB[kk]; }
      }
    }
    // per-wave partial norm sums -> LDS
    ssq += __shfl_xor(ssq, 16); ssq += __shfl_xor(ssq, 32);
    ssk += __shfl_xor(ssk, 16); ssk += __shfl_xor(ssk, 32);
    ssv += __shfl_xor(ssv, 16); ssv += __shfl_xor(ssv, 32);
    if (l < 16) {
      if (wp == 0) { pQ[n_mine] = ssq; pK0[n_mine] = ssk; }
      else         { pK1[n_mine] = ssk; pV[n_mine] = ssv; }
    }
    __syncthreads();   // B1: q,k,v buffers + norm partials complete

    if (t < 128) {
      const float iq = 1.0f / fmaxf(sqrtf(pQ[t]), 1e-12f);
      const float ik = 1.0f / fmaxf(sqrtf(pK0[t] + pK1[t]), 1e-12f);
      const float iv = 1.0f / fmaxf(sqrtf(pV[t]), 1e-12f);
      pQ[t] = iq;
      fA[4 * t + 0] = ik * F_SCALING;
      fA[4 * t + 1] = sSW[t];
      fA[4 * t + 2] = iv;
      fA[4 * t + 3] = sRX[t];
      fB[2 * t + 0] = sRY[t];
      fB[2 * t + 1] = sRZ[t];
    }
    // hoist v and q fragments (rows n_mine; both wp same)
    bf16x8 vf[4], qf[4];
#pragma unroll
    for (int kk = 0; kk < 4; ++kk) {
      vf[kk] = *(const bf16x8*)(bufV + n_mine * ROWP + 8 * lg + 32 * kk);
      qf[kk] = *(const bf16x8*)(bufQ + n_mine * ROWP + 8 * lg + 32 * kk);
    }
    __syncthreads();   // B2: hoists + factor tables done; bufV may be overwritten

    // ---- VW = v @ W_out -> VW^T in bufV; wave handles e-tiles {4wp..4wp+3} ----
#pragma unroll
    for (int i = 0; i < 2; ++i) {
      const int etA = 4 * wp + i, etB = 4 * wp + 2 + i;
      bf16x8 bwA[4], bwB[4];
#pragma unroll
      for (int kk = 0; kk < 4; ++kk) {
        bwA[kk] = wt_frag<WS>(wtO, WoutL, 16 * etA + lc, 8 * lg + 32 * kk, 128);
        bwB[kk] = wt_frag<WS>(wtO, WoutL, 16 * etB + lc, 8 * lg + 32 * kk, 128);
      }
      f32x4 aA = {0, 0, 0, 0}, aB = {0, 0, 0, 0};
#pragma unroll
      for (int kk = 0; kk < 4; ++kk) {
        aA = MFMA(vf[kk], bwA[kk], aA);
        aB = MFMA(vf[kk], bwB[kk], aB);
      }
      *(ushort4*)(bufV + (16 * etA + lc) * ROWP + 16 * wh + 4 * lg) = pack4(aA[0], aA[1], aA[2], aA[3]);
      *(ushort4*)(bufV + (16 * etB + lc) * ROWP + 16 * wh + 4 * lg) = pack4(aB[0], aB[1], aB[2], aB[3]);
    }

    // ---- S^T = k * q^T ; wave handles m-tiles {4wp..4wp+3} ----
    f32x4 sacc[4];
#pragma unroll
    for (int i = 0; i < 2; ++i) {
      const int mtA = 4 * wp + i, mtB = 4 * wp + 2 + i;
      bf16x8 kA[4], kB[4];
#pragma unroll
      for (int kk = 0; kk < 4; ++kk) {
        kA[kk] = *(const bf16x8*)(bufK + (16 * mtA + lc) * ROWP + 8 * lg + 32 * kk);
        kB[kk] = *(const bf16x8*)(bufK + (16 * mtB + lc) * ROWP + 8 * lg + 32 * kk);
      }
      f32x4 aA = {0, 0, 0, 0}, aB = {0, 0, 0, 0};
#pragma unroll
      for (int kk = 0; kk < 4; ++kk) {
        aA = MFMA(kA[kk], qf[kk], aA);
        aB = MFMA(kB[kk], qf[kk], aB);
      }
      sacc[i] = aA; sacc[2 + i] = aB;
    }

    // ---- softmax prefactors (lane owns row n_mine, 16 of 128 m's) ----
    {
      const float iqn = pQ[n_mine];
      const float swn = sSW[n_mine];
      const float rxn = sRX[n_mine], ryn = sRY[n_mine], rzn = sRZ[n_mine];
      float sum = 0.0f;
#pragma unroll
      for (int ml = 0; ml < 4; ++ml) {
#pragma unroll
        for (int r2 = 0; r2 < 4; ++r2) {
          const int m = 16 * (4 * wp + ml) + 4 * lg + r2;
          const float4 a4 = *(const float4*)&fA[4 * m];
          const float2 b2 = *(const float2*)&fB[2 * m];
          const float sws = swn * a4.y;
          const float lgt = (sacc[ml][r2] * iqn * a4.x + F_SHIFT) * sws - F_SHIFT;
          const float e = __expf(lgt);   // logits in [-20, 0.09]
          sum += e;
          const float ang = rxn * a4.w + ryn * b2.x + rzn * b2.y;
          sacc[ml][r2] = e * sws * a4.z * ang;
        }
      }
      sum += __shfl_xor(sum, 16); sum += __shfl_xor(sum, 32);
      if (l < 16) sPS[wp * 128 + n_mine] = sum;
      __syncthreads();   // B3: softmax partials + VW^T stores complete
      const float fac = sMK[n_mine] / (sPS[n_mine] + sPS[128 + n_mine]);
#pragma unroll
      for (int ml = 0; ml < 4; ++ml) {
        *(ushort4*)(bufQ + n_mine * ROWP + 16 * (4 * wp + ml) + 4 * lg) =
            pack4(sacc[ml][0] * fac, sacc[ml][1] * fac, sacc[ml][2] * fac, sacc[ml][3] * fac);
      }
    }
    __syncthreads();   // B4: P complete

    // ---- out = P @ VW ; wave handles e-tiles {4wp..4wp+3}, rows 16wh.. ----
    bf16x8 pf[4];
#pragma unroll
    for (int kk = 0; kk < 4; ++kk)
      pf[kk] = *(const bf16x8*)(bufQ + n_mine * ROWP + 8 * lg + 32 * kk);
    f32x4 oacc[4];
#pragma unroll
    for (int i = 0; i < 2; ++i) {
      const int etA = 4 * wp + i, etB = 4 * wp + 2 + i;
      bf16x8 bA[4], bB[4];
#pragma unroll
      for (int kk = 0; kk < 4; ++kk) {
        bA[kk] = *(const bf16x8*)(bufV + (16 * etA + lc) * ROWP + 8 * lg + 32 * kk);
        bB[kk] = *(const bf16x8*)(bufV + (16 * etB + lc) * ROWP + 8 * lg + 32 * kk);
      }
      f32x4 aA = {0, 0, 0, 0}, aB = {0, 0, 0, 0};
#pragma unroll
      for (int kk = 0; kk < 4; ++kk) {
        aA = MFMA(pf[kk], bA[kk], aA);
        aB = MFMA(pf[kk], bB[kk], aB);
      }
      oacc[i] = aA; oacc[2 + i] = aB;
    }

    // ---- epilogue: +b_out +residual, LN (cross-wave partials), write x' ----
    {
      float bo4[4], g4[4], be4[4];
#pragma unroll
      for (int ct = 0; ct < 4; ++ct) {
        const int e = 16 * (4 * wp + ct) + lc;
        bo4[ct] = boutL[e]; g4[ct] = lngL[e]; be4[ct] = lnbL[e];
      }
      float vals[4][4];
#pragma unroll
      for (int r2 = 0; r2 < 4; ++r2) {
        const int n = 16 * wh + 4 * lg + r2;
        const float* xr = xsrc + (size_t)n * 128;
        float s1 = 0.0f, s2 = 0.0f;
#pragma unroll
        for (int ct = 0; ct < 4; ++ct) {
          const float v = oacc[ct][r2] + bo4[ct] + xr[16 * (4 * wp + ct) + lc];
          vals[r2][ct] = v; s1 += v; s2 += v * v;
        }
        s1 += __shfl_xor(s1, 1); s1 += __shfl_xor(s1, 2);
        s1 += __shfl_xor(s1, 4); s1 += __shfl_xor(s1, 8);
        s2 += __shfl_xor(s2, 1); s2 += __shfl_xor(s2, 2);
        s2 += __shfl_xor(s2, 4); s2 += __shfl_xor(s2, 8);
        if (lc == 0) { sL1[wp * 128 + n] = s1; sL2[wp * 128 + n] = s2; }
      }
      __syncthreads();   // B5: LN partials complete
#pragma unroll
      for (int r2 = 0; r2 < 4; ++r2) {
        const int n = 16 * wh + 4 * lg + r2;
        const float s1 = sL1[n] + sL1[128 + n];
        const float s2 = sL2[n] + sL2[128 + n];
        const float mu = s1 * (1.0f / 128.0f);
        const float rs = rsqrtf(s2 * (1.0f / 128.0f) - mu * mu + F_LNEPS);
        float* orow = xout + bb + (size_t)n * 128;
#pragma unroll
        for (int ct = 0; ct < 4; ++ct)
          orow[16 * (4 * wp + ct) + lc] = (vals[r2][ct] - mu) * rs * g4[ct] + be4[ct];
      }
    }
    __threadfence_block();
    __syncthreads();   // B6: layer boundary
  }
}

extern "C" void kernel_launch(void* const* d_in, const int* in_sizes, int n_in,
                              void* d_out, int out_size, void* d_ws, size_t ws_size,
                              hipStream_t stream) {
  const float* G    = (const float*)d_in[0];
  const int*   msk  = (const int*)d_in[1];
  const float* r3   = (const float*)d_in[2];
  const float* swg  = (const float*)d_in[3];
  const float* Win  = (const float*)d_in[4];
  const float* bin  = (const float*)d_in[5];
  const float* Wout = (const float*)d_in[6];
  const float* bout = (const float*)d_in[7];
  const float* lng  = (const float*)d_in[8];
  const float* lnb  = (const float*)d_in[9];
  float* xout = (float*)d_out;

  const int B = in_sizes[0] / (128 * 128);
  const bool ws_ok = ws_size >= (WTI_ELEMS + WTO_ELEMS) * sizeof(ushort_t);
  ushort_t* wtI = (ushort_t*)d_ws;
  ushort_t* wtO = wtI + WTI_ELEMS;

  if (ws_ok) {
    prep_weights<<<dim3(384), dim3(256), 0, stream>>>(Win, Wout, wtI, wtO);
    hipFuncSetAttribute(reinterpret_cast<const void*>(ngatt_mfma<true>),
                        hipFuncAttributeMaxDynamicSharedMemorySize, LDS_BYTES);
    ngatt_mfma<true><<<dim3(B), dim3(1024), LDS_BYTES, stream>>>(
        G, msk, r3, swg, Win, bin, Wout, bout, lng, lnb, wtI, wtO, xout);
  } else {
    hipFuncSetAttribute(reinterpret_cast<const void*>(ngatt_mfma<false>),
                        hipFuncAttributeMaxDynamicSharedMemorySize, LDS_BYTES);
    ngatt_mfma<false><<<dim3(B), dim3(1024), LDS_BYTES, stream>>>(
        G, msk, r3, swg, Win, bin, Wout, bout, lng, lnb, nullptr, nullptr, xout);
  }
}

// Round 4
// 3725.880 us; speedup vs baseline: 1.1809x; 1.1809x over previous
//
#include <hip/hip_runtime.h>
#include <hip/hip_bf16.h>
#include <math.h>

// NeighborGatedAttention, bf16-MFMA, 2-blocks/CU version.
// L=2, B=8192, NNEI=128, EMB=HID=128. One block (512 thr = 8 waves) per b.
// LDS cut to 77.3 KB (2 big buffers) so 2 independent blocks fit per CU
// (4 waves/SIMD). Buffer lifetimes: bufA: q -> v -> VW^T ; bufB: k -> P.
// 1/|v| is folded into the VW^T store epilogue (VW row m *= iv[m]) instead of
// P, which removes the need for q,k,v to be live simultaneously.
// All GEMMs v_mfma_f32_16x16x32_bf16; norms from fp32 accs; softmax/LN fp32.

typedef __attribute__((ext_vector_type(8))) short bf16x8; // 8 bf16 = 4 VGPR
typedef __attribute__((ext_vector_type(4))) float f32x4;
typedef unsigned short ushort_t;

constexpr float F_SHIFT   = 20.0f;
constexpr float F_SCALING = 0.08838834764831845f; // 128^-0.5
constexpr float F_LNEPS   = 1e-5f;

constexpr int ROWP = 136;                 // ushort row pitch (272B)
constexpr int BUF_US = 128 * ROWP;        // 17408 ushorts per buffer
constexpr size_t WTI_ELEMS = 2 * 384 * 128;
constexpr size_t WTO_ELEMS = 2 * 128 * 128;
// floats: pQ,pK,pV,sIV (512) fA(512) fB(256) sSW,sMK,sRX,sRY,sRZ(640)
constexpr int NFLOATS = 512 + 512 + 256 + 640;            // 1920
constexpr int LDS_BYTES = 2 * BUF_US * 2 + NFLOATS * 4;   // 77312 <= 80KB

#define MFMA(a, b, c) __builtin_amdgcn_mfma_f32_16x16x32_bf16(a, b, c, 0, 0, 0)

__device__ __forceinline__ ushort_t f2bf(float f) {
  __hip_bfloat16 h = __float2bfloat16(f);
  return *reinterpret_cast<ushort_t*>(&h);
}
__device__ __forceinline__ ushort4 pack4(float a, float b, float c, float d) {
  return make_ushort4(f2bf(a), f2bf(b), f2bf(c), f2bf(d));
}

// A/B fragment from pre-transposed bf16 weights (WS) or fp32 gather fallback.
template <bool WS>
__device__ __forceinline__ bf16x8 wt_frag(const ushort_t* __restrict__ wt,
                                          const float* __restrict__ W,
                                          int r, int c, int ldW) {
  if constexpr (WS) {
    return *(const bf16x8*)(wt + r * 128 + c);
  } else {
    bf16x8 f;
#pragma unroll
    for (int j = 0; j < 8; ++j) f[j] = (short)f2bf(W[(size_t)(c + j) * ldW + r]);
    return f;
  }
}

__global__ void prep_weights(const float* __restrict__ Win, const float* __restrict__ Wout,
                             ushort_t* __restrict__ wtI, ushort_t* __restrict__ wtO) {
  const int i = blockIdx.x * 256 + threadIdx.x;
  if (i < (int)WTI_ELEMS) {   // wtI[l][h][e] = bf16(Win[l][e][h])
    const int l = i / (384 * 128), r = i % (384 * 128), h = r >> 7, e = r & 127;
    wtI[i] = f2bf(Win[l * (128 * 384) + e * 384 + h]);
  }
  if (i < (int)WTO_ELEMS) {   // wtO[l][e][h] = bf16(Wout[l][h][e])
    const int l = i >> 14, r = i & 16383, e = r >> 7, h = r & 127;
    wtO[i] = f2bf(Wout[(l << 14) + h * 128 + e]);
  }
}

// qkv tile epilogue: +bias, accumulate squared-norm, pack bf16x4 to LDS row.
__device__ __forceinline__ void qkv_epi(ushort_t* dst, int ti, const f32x4& acc,
                                        const float* __restrict__ bias,
                                        int n_mine, int lg, float& ss) {
  const float4 bi = *(const float4*)&bias[16 * ti + 4 * lg];
  const float v0 = acc[0] + bi.x, v1 = acc[1] + bi.y, v2 = acc[2] + bi.z, v3 = acc[3] + bi.w;
  ss += v0 * v0 + v1 * v1 + v2 * v2 + v3 * v3;
  *(ushort4*)(dst + n_mine * ROWP + 16 * ti + 4 * lg) = pack4(v0, v1, v2, v3);
}

template <bool WS>
__global__ __launch_bounds__(512, 4)
void ngatt_mfma(const float* __restrict__ G, const int* __restrict__ nmask,
                const float* __restrict__ r3, const float* __restrict__ swg,
                const float* __restrict__ Win, const float* __restrict__ bin,
                const float* __restrict__ Wout, const float* __restrict__ bout,
                const float* __restrict__ lng, const float* __restrict__ lnb,
                const ushort_t* __restrict__ wtin, const ushort_t* __restrict__ wtout,
                float* __restrict__ xout) {
  extern __shared__ char smem[];
  ushort_t* bufA = (ushort_t*)smem;            // q -> v -> VW^T
  ushort_t* bufB = bufA + BUF_US;              // k -> P
  float* pQ  = (float*)(bufB + BUF_US);        // |q|^2 partial -> 1/|q|
  float* pK  = pQ  + 128;
  float* pV  = pK  + 128;
  float* sIV = pV  + 128;                      // 1/|v|
  float* fA  = sIV + 128;                      // [128]x4 {ik*SCL, sw, 0, rx}
  float* fB  = fA  + 512;                      // [128]x2 {ry, rz}
  float* sSW = fB  + 256;
  float* sMK = sSW + 128;
  float* sRX = sMK + 128;
  float* sRY = sRX + 128;
  float* sRZ = sRY + 128;

  const int b = blockIdx.x, t = threadIdx.x;
  const int w = t >> 6, l = t & 63, lc = l & 15, lg = l >> 4;
  const size_t bb = (size_t)b * (128 * 128);
  const int n_mine = 16 * w + lc;

  if (t < 128) {
    const size_t gi = (size_t)b * 128 + t;
    sSW[t] = swg[gi];
    sMK[t] = nmask[gi] ? 1.0f : 0.0f;
    sRX[t] = r3[gi * 3 + 0]; sRY[t] = r3[gi * 3 + 1]; sRZ[t] = r3[gi * 3 + 2];
  }
  __syncthreads();

  for (int layer = 0; layer < 2; ++layer) {
    const float* xsrc = layer ? (xout + bb) : (G + bb);
    const ushort_t* wtI = wtin + (size_t)layer * 384 * 128;
    const ushort_t* wtO = wtout + (size_t)layer * 128 * 128;
    const float* WinL  = Win  + (size_t)layer * 128 * 384;
    const float* WoutL = Wout + (size_t)layer * 128 * 128;
    const float* binL  = bin  + layer * 384;
    const float* boutL = bout + layer * 128;
    const float* lngL  = lng  + layer * 128;
    const float* lnbL  = lnb  + layer * 128;

    // ---- hoist x B-fragments (col n_mine), reused by all qkv tiles ----
    bf16x8 xf[4];
    {
      const float* xr = xsrc + (size_t)n_mine * 128 + 8 * lg;
#pragma unroll
      for (int kk = 0; kk < 4; ++kk) {
        const float4 a = *(const float4*)(xr + 32 * kk);
        const float4 c = *(const float4*)(xr + 32 * kk + 4);
        bf16x8 f;
        f[0] = (short)f2bf(a.x); f[1] = (short)f2bf(a.y);
        f[2] = (short)f2bf(a.z); f[3] = (short)f2bf(a.w);
        f[4] = (short)f2bf(c.x); f[5] = (short)f2bf(c.y);
        f[6] = (short)f2bf(c.z); f[7] = (short)f2bf(c.w);
        xf[kk] = f;
      }
    }

    // ---- pass 1: q (tiles 0..7) -> bufA, k (tiles 8..15) -> bufB ----
    float ssq = 0.f, ssk = 0.f;
    {
      bf16x8 awA[4], awB[4], nwA[4], nwB[4];
#pragma unroll
      for (int kk = 0; kk < 4; ++kk) {
        awA[kk] = wt_frag<WS>(wtI, WinL, lc,       8 * lg + 32 * kk, 384);
        awB[kk] = wt_frag<WS>(wtI, WinL, 128 + lc, 8 * lg + 32 * kk, 384);
      }
      for (int i = 0; i < 8; ++i) {
        if (i < 7) {
#pragma unroll
          for (int kk = 0; kk < 4; ++kk) {
            nwA[kk] = wt_frag<WS>(wtI, WinL, 16 * (i + 1) + lc,       8 * lg + 32 * kk, 384);
            nwB[kk] = wt_frag<WS>(wtI, WinL, 128 + 16 * (i + 1) + lc, 8 * lg + 32 * kk, 384);
          }
        }
        f32x4 aA = {0, 0, 0, 0}, aB = {0, 0, 0, 0};
#pragma unroll
        for (int kk = 0; kk < 4; ++kk) {
          aA = MFMA(awA[kk], xf[kk], aA);
          aB = MFMA(awB[kk], xf[kk], aB);
        }
        qkv_epi(bufA, i, aA, binL,       n_mine, lg, ssq);
        qkv_epi(bufB, i, aB, binL + 128, n_mine, lg, ssk);
#pragma unroll
        for (int kk = 0; kk < 4; ++kk) { awA[kk] = nwA[kk]; awB[kk] = nwB[kk]; }
      }
    }
    ssq += __shfl_xor(ssq, 16); ssq += __shfl_xor(ssq, 32);
    ssk += __shfl_xor(ssk, 16); ssk += __shfl_xor(ssk, 32);
    if (l < 16) { pQ[n_mine] = ssq; pK[n_mine] = ssk; }
    __syncthreads();   // B1: q,k complete + norm partials

    if (t < 128) {
      pQ[t] = 1.0f / fmaxf(sqrtf(pQ[t]), 1e-12f);
      fA[4 * t + 0] = (1.0f / fmaxf(sqrtf(pK[t]), 1e-12f)) * F_SCALING;
      fA[4 * t + 1] = sSW[t];
      fA[4 * t + 2] = 0.0f;
      fA[4 * t + 3] = sRX[t];
      fB[2 * t + 0] = sRY[t];
      fB[2 * t + 1] = sRZ[t];
    }
    // hoist q fragments (wave's own rows n_mine)
    bf16x8 qf[4];
#pragma unroll
    for (int kk = 0; kk < 4; ++kk)
      qf[kk] = *(const bf16x8*)(bufA + n_mine * ROWP + 8 * lg + 32 * kk);
    __syncthreads();   // B2: qf hoisted by all; factor tables ready; bufA free

    // ---- pass 2: v (tiles 16..23) -> bufA ----
    float ssv = 0.f;
    for (int i = 0; i < 4; ++i) {
      bf16x8 bwA[4], bwB[4];
#pragma unroll
      for (int kk = 0; kk < 4; ++kk) {
        bwA[kk] = wt_frag<WS>(wtI, WinL, 256 + 16 * i + lc, 8 * lg + 32 * kk, 384);
        bwB[kk] = wt_frag<WS>(wtI, WinL, 320 + 16 * i + lc, 8 * lg + 32 * kk, 384);
      }
      f32x4 aA = {0, 0, 0, 0}, aB = {0, 0, 0, 0};
#pragma unroll
      for (int kk = 0; kk < 4; ++kk) {
        aA = MFMA(bwA[kk], xf[kk], aA);
        aB = MFMA(bwB[kk], xf[kk], aB);
      }
      qkv_epi(bufA, i,     aA, binL + 256, n_mine, lg, ssv);
      qkv_epi(bufA, i + 4, aB, binL + 256, n_mine, lg, ssv);
    }
    ssv += __shfl_xor(ssv, 16); ssv += __shfl_xor(ssv, 32);
    if (l < 16) pV[n_mine] = ssv;

    // ---- S^T = k * q^T (reads bufB + qf), softmax prefactors in regs ----
    f32x4 sacc[8];
#pragma unroll
    for (int i = 0; i < 4; ++i) {
      bf16x8 kA[4], kB[4];
#pragma unroll
      for (int kk = 0; kk < 4; ++kk) {
        kA[kk] = *(const bf16x8*)(bufB + (16 * i + lc)       * ROWP + 8 * lg + 32 * kk);
        kB[kk] = *(const bf16x8*)(bufB + (16 * (i + 4) + lc) * ROWP + 8 * lg + 32 * kk);
      }
      f32x4 aA = {0, 0, 0, 0}, aB = {0, 0, 0, 0};
#pragma unroll
      for (int kk = 0; kk < 4; ++kk) {
        aA = MFMA(kA[kk], qf[kk], aA);
        aB = MFMA(kB[kk], qf[kk], aB);
      }
      sacc[i] = aA; sacc[i + 4] = aB;
    }
    {
      const float iqn = pQ[n_mine];
      const float swn = sSW[n_mine];
      const float rxn = sRX[n_mine], ryn = sRY[n_mine], rzn = sRZ[n_mine];
      float sum = 0.0f;
#pragma unroll
      for (int mt = 0; mt < 8; ++mt) {
#pragma unroll
        for (int r2 = 0; r2 < 4; ++r2) {
          const int m = 16 * mt + 4 * lg + r2;
          const float4 a4 = *(const float4*)&fA[4 * m];
          const float2 b2 = *(const float2*)&fB[2 * m];
          const float sws = swn * a4.y;
          const float lgt = (sacc[mt][r2] * iqn * a4.x + F_SHIFT) * sws - F_SHIFT;
          const float e = __expf(lgt);   // logits in [-20, 0.09]
          sum += e;
          const float ang = rxn * a4.w + ryn * b2.x + rzn * b2.y;
          sacc[mt][r2] = e * sws * ang;  // 1/|v| folded into VW^T instead
        }
      }
      sum += __shfl_xor(sum, 16); sum += __shfl_xor(sum, 32);
      const float fac = sMK[n_mine] / sum;
#pragma unroll
      for (int mt = 0; mt < 8; ++mt) {
#pragma unroll
        for (int r2 = 0; r2 < 4; ++r2) sacc[mt][r2] *= fac;
      }
    }
    __syncthreads();   // B3: v complete; all S reads of bufB done; pV written

    if (t < 128) sIV[t] = 1.0f / fmaxf(sqrtf(pV[t]), 1e-12f);
    // store P -> bufB (own rows)
#pragma unroll
    for (int mt = 0; mt < 8; ++mt) {
      *(ushort4*)(bufB + n_mine * ROWP + 16 * mt + 4 * lg) =
          pack4(sacc[mt][0], sacc[mt][1], sacc[mt][2], sacc[mt][3]);
    }
    // hoist v fragments (wave's own rows)
    bf16x8 vf[4];
#pragma unroll
    for (int kk = 0; kk < 4; ++kk)
      vf[kk] = *(const bf16x8*)(bufA + n_mine * ROWP + 8 * lg + 32 * kk);
    __syncthreads();   // B4: P stored, vf hoisted by all, sIV ready; bufA free

    // hoist P fragments (own rows; stored by self before B4)
    bf16x8 pf[4];
#pragma unroll
    for (int kk = 0; kk < 4; ++kk)
      pf[kk] = *(const bf16x8*)(bufB + n_mine * ROWP + 8 * lg + 32 * kk);

    // ---- VW^T = (v @ W_out)^T * iv  -> bufA ----
    {
      const float4 ivm = *(const float4*)&sIV[16 * w + 4 * lg];
#pragma unroll
      for (int i = 0; i < 4; ++i) {
        bf16x8 bwA[4], bwB[4];
#pragma unroll
        for (int kk = 0; kk < 4; ++kk) {
          bwA[kk] = wt_frag<WS>(wtO, WoutL, 16 * i + lc,       8 * lg + 32 * kk, 128);
          bwB[kk] = wt_frag<WS>(wtO, WoutL, 16 * (i + 4) + lc, 8 * lg + 32 * kk, 128);
        }
        f32x4 aA = {0, 0, 0, 0}, aB = {0, 0, 0, 0};
#pragma unroll
        for (int kk = 0; kk < 4; ++kk) {
          aA = MFMA(vf[kk], bwA[kk], aA);
          aB = MFMA(vf[kk], bwB[kk], aB);
        }
        *(ushort4*)(bufA + (16 * i + lc) * ROWP + 16 * w + 4 * lg) =
            pack4(aA[0] * ivm.x, aA[1] * ivm.y, aA[2] * ivm.z, aA[3] * ivm.w);
        *(ushort4*)(bufA + (16 * (i + 4) + lc) * ROWP + 16 * w + 4 * lg) =
            pack4(aB[0] * ivm.x, aB[1] * ivm.y, aB[2] * ivm.z, aB[3] * ivm.w);
      }
    }
    __syncthreads();   // B5: VW^T complete

    // ---- out = P @ VW ; wave owns rows 16w..16w+15, all 8 e-tiles ----
    f32x4 oacc[8];
#pragma unroll
    for (int i = 0; i < 4; ++i) {
      bf16x8 bA[4], bB[4];
#pragma unroll
      for (int kk = 0; kk < 4; ++kk) {
        bA[kk] = *(const bf16x8*)(bufA + (16 * i + lc)       * ROWP + 8 * lg + 32 * kk);
        bB[kk] = *(const bf16x8*)(bufA + (16 * (i + 4) + lc) * ROWP + 8 * lg + 32 * kk);
      }
      f32x4 aA = {0, 0, 0, 0}, aB = {0, 0, 0, 0};
#pragma unroll
      for (int kk = 0; kk < 4; ++kk) {
        aA = MFMA(pf[kk], bA[kk], aA);
        aB = MFMA(pf[kk], bB[kk], aB);
      }
      oacc[i] = aA; oacc[i + 4] = aB;
    }

    // ---- epilogue: +b_out +residual(fp32), LayerNorm, write x' ----
    {
      float bo8[8], g8[8], be8[8];
#pragma unroll
      for (int ct = 0; ct < 8; ++ct) {
        const int e = 16 * ct + lc;
        bo8[ct] = boutL[e]; g8[ct] = lngL[e]; be8[ct] = lnbL[e];
      }
#pragma unroll
      for (int r2 = 0; r2 < 4; ++r2) {
        const int n = 16 * w + 4 * lg + r2;
        const float* xr = xsrc + (size_t)n * 128;
        float vals[8];
        float s1 = 0.0f, s2 = 0.0f;
#pragma unroll
        for (int ct = 0; ct < 8; ++ct) {
          const float v = oacc[ct][r2] + bo8[ct] + xr[16 * ct + lc];
          vals[ct] = v; s1 += v; s2 += v * v;
        }
        s1 += __shfl_xor(s1, 1); s1 += __shfl_xor(s1, 2);
        s1 += __shfl_xor(s1, 4); s1 += __shfl_xor(s1, 8);
        s2 += __shfl_xor(s2, 1); s2 += __shfl_xor(s2, 2);
        s2 += __shfl_xor(s2, 4); s2 += __shfl_xor(s2, 8);
        const float mu = s1 * (1.0f / 128.0f);
        const float rs = rsqrtf(s2 * (1.0f / 128.0f) - mu * mu + F_LNEPS);
        float* orow = xout + bb + (size_t)n * 128;
#pragma unroll
        for (int ct = 0; ct < 8; ++ct)
          orow[16 * ct + lc] = (vals[ct] - mu) * rs * g8[ct] + be8[ct];
      }
    }
    __syncthreads();   // B6: layer boundary (buffers reused; xout -> next xsrc)
  }
}

extern "C" void kernel_launch(void* const* d_in, const int* in_sizes, int n_in,
                              void* d_out, int out_size, void* d_ws, size_t ws_size,
                              hipStream_t stream) {
  const float* G    = (const float*)d_in[0];
  const int*   msk  = (const int*)d_in[1];
  const float* r3   = (const float*)d_in[2];
  const float* swg  = (const float*)d_in[3];
  const float* Win  = (const float*)d_in[4];
  const float* bin  = (const float*)d_in[5];
  const float* Wout = (const float*)d_in[6];
  const float* bout = (const float*)d_in[7];
  const float* lng  = (const float*)d_in[8];
  const float* lnb  = (const float*)d_in[9];
  float* xout = (float*)d_out;

  const int B = in_sizes[0] / (128 * 128);
  const bool ws_ok = ws_size >= (WTI_ELEMS + WTO_ELEMS) * sizeof(ushort_t);
  ushort_t* wtI = (ushort_t*)d_ws;
  ushort_t* wtO = wtI + WTI_ELEMS;

  if (ws_ok) {
    prep_weights<<<dim3(384), dim3(256), 0, stream>>>(Win, Wout, wtI, wtO);
    hipFuncSetAttribute(reinterpret_cast<const void*>(ngatt_mfma<true>),
                        hipFuncAttributeMaxDynamicSharedMemorySize, LDS_BYTES);
    ngatt_mfma<true><<<dim3(B), dim3(512), LDS_BYTES, stream>>>(
        G, msk, r3, swg, Win, bin, Wout, bout, lng, lnb, wtI, wtO, xout);
  } else {
    hipFuncSetAttribute(reinterpret_cast<const void*>(ngatt_mfma<false>),
                        hipFuncAttributeMaxDynamicSharedMemorySize, LDS_BYTES);
    ngatt_mfma<false><<<dim3(B), dim3(512), LDS_BYTES, stream>>>(
        G, msk, r3, swg, Win, bin, Wout, bout, lng, lnb, nullptr, nullptr, xout);
  }
}

// Round 5
// 2887.376 us; speedup vs baseline: 1.5239x; 1.2904x over previous
//
#include <hip/hip_runtime.h>
#include <hip/hip_bf16.h>
#include <math.h>

// NeighborGatedAttention, bf16-MFMA, 2-blocks/CU version.
// L=2, B=8192, NNEI=128, EMB=HID=128. One block (512 thr = 8 waves) per b.
// LDS 77.3 KB (2 big buffers) so 2 blocks fit per CU (4 waves/SIMD).
// Buffer lifetimes: bufA: q -> v -> VW^T ; bufB: k -> P.
// 1/|v| folded into the VW^T store epilogue (VW row m *= iv[m]).
// __launch_bounds__(512, 2): 2nd arg empirically behaves as min BLOCKS/CU
// (R2 (512,2)->124 VGPR; R4 (512,4)->64 VGPR + spills). 2 blocks -> 128 cap.
// All GEMMs v_mfma_f32_16x16x32_bf16; norms from fp32 accs; softmax/LN fp32.

typedef __attribute__((ext_vector_type(8))) short bf16x8; // 8 bf16 = 4 VGPR
typedef __attribute__((ext_vector_type(4))) float f32x4;
typedef unsigned short ushort_t;

constexpr float F_SHIFT   = 20.0f;
constexpr float F_SCALING = 0.08838834764831845f; // 128^-0.5
constexpr float F_LNEPS   = 1e-5f;

constexpr int ROWP = 136;                 // ushort row pitch (272B)
constexpr int BUF_US = 128 * ROWP;        // 17408 ushorts per buffer
constexpr size_t WTI_ELEMS = 2 * 384 * 128;
constexpr size_t WTO_ELEMS = 2 * 128 * 128;
// floats: pQ,pK,pV,sIV (512) fA(512) fB(256) sSW,sMK,sRX,sRY,sRZ(640)
constexpr int NFLOATS = 512 + 512 + 256 + 640;            // 1920
constexpr int LDS_BYTES = 2 * BUF_US * 2 + NFLOATS * 4;   // 77312 <= 80KB

#define MFMA(a, b, c) __builtin_amdgcn_mfma_f32_16x16x32_bf16(a, b, c, 0, 0, 0)

__device__ __forceinline__ ushort_t f2bf(float f) {
  __hip_bfloat16 h = __float2bfloat16(f);
  return *reinterpret_cast<ushort_t*>(&h);
}
__device__ __forceinline__ ushort4 pack4(float a, float b, float c, float d) {
  return make_ushort4(f2bf(a), f2bf(b), f2bf(c), f2bf(d));
}

// A/B fragment from pre-transposed bf16 weights (WS) or fp32 gather fallback.
template <bool WS>
__device__ __forceinline__ bf16x8 wt_frag(const ushort_t* __restrict__ wt,
                                          const float* __restrict__ W,
                                          int r, int c, int ldW) {
  if constexpr (WS) {
    return *(const bf16x8*)(wt + r * 128 + c);
  } else {
    bf16x8 f;
#pragma unroll
    for (int j = 0; j < 8; ++j) f[j] = (short)f2bf(W[(size_t)(c + j) * ldW + r]);
    return f;
  }
}

__global__ void prep_weights(const float* __restrict__ Win, const float* __restrict__ Wout,
                             ushort_t* __restrict__ wtI, ushort_t* __restrict__ wtO) {
  const int i = blockIdx.x * 256 + threadIdx.x;
  if (i < (int)WTI_ELEMS) {   // wtI[l][h][e] = bf16(Win[l][e][h])
    const int l = i / (384 * 128), r = i % (384 * 128), h = r >> 7, e = r & 127;
    wtI[i] = f2bf(Win[l * (128 * 384) + e * 384 + h]);
  }
  if (i < (int)WTO_ELEMS) {   // wtO[l][e][h] = bf16(Wout[l][h][e])
    const int l = i >> 14, r = i & 16383, e = r >> 7, h = r & 127;
    wtO[i] = f2bf(Wout[(l << 14) + h * 128 + e]);
  }
}

// qkv tile epilogue: +bias, accumulate squared-norm, pack bf16x4 to LDS row.
__device__ __forceinline__ void qkv_epi(ushort_t* dst, int ti, const f32x4& acc,
                                        const float* __restrict__ bias,
                                        int n_mine, int lg, float& ss) {
  const float4 bi = *(const float4*)&bias[16 * ti + 4 * lg];
  const float v0 = acc[0] + bi.x, v1 = acc[1] + bi.y, v2 = acc[2] + bi.z, v3 = acc[3] + bi.w;
  ss += v0 * v0 + v1 * v1 + v2 * v2 + v3 * v3;
  *(ushort4*)(dst + n_mine * ROWP + 16 * ti + 4 * lg) = pack4(v0, v1, v2, v3);
}

template <bool WS>
__global__ __launch_bounds__(512, 2)
void ngatt_mfma(const float* __restrict__ G, const int* __restrict__ nmask,
                const float* __restrict__ r3, const float* __restrict__ swg,
                const float* __restrict__ Win, const float* __restrict__ bin,
                const float* __restrict__ Wout, const float* __restrict__ bout,
                const float* __restrict__ lng, const float* __restrict__ lnb,
                const ushort_t* __restrict__ wtin, const ushort_t* __restrict__ wtout,
                float* __restrict__ xout) {
  extern __shared__ char smem[];
  ushort_t* bufA = (ushort_t*)smem;            // q -> v -> VW^T
  ushort_t* bufB = bufA + BUF_US;              // k -> P
  float* pQ  = (float*)(bufB + BUF_US);        // |q|^2 partial -> 1/|q|
  float* pK  = pQ  + 128;
  float* pV  = pK  + 128;
  float* sIV = pV  + 128;                      // 1/|v|
  float* fA  = sIV + 128;                      // [128]x4 {ik*SCL, sw, 0, rx}
  float* fB  = fA  + 512;                      // [128]x2 {ry, rz}
  float* sSW = fB  + 256;
  float* sMK = sSW + 128;
  float* sRX = sMK + 128;
  float* sRY = sRX + 128;
  float* sRZ = sRY + 128;

  const int b = blockIdx.x, t = threadIdx.x;
  const int w = t >> 6, l = t & 63, lc = l & 15, lg = l >> 4;
  const size_t bb = (size_t)b * (128 * 128);
  const int n_mine = 16 * w + lc;

  if (t < 128) {
    const size_t gi = (size_t)b * 128 + t;
    sSW[t] = swg[gi];
    sMK[t] = nmask[gi] ? 1.0f : 0.0f;
    sRX[t] = r3[gi * 3 + 0]; sRY[t] = r3[gi * 3 + 1]; sRZ[t] = r3[gi * 3 + 2];
  }
  __syncthreads();

  for (int layer = 0; layer < 2; ++layer) {
    const float* xsrc = layer ? (xout + bb) : (G + bb);
    const ushort_t* wtI = wtin + (size_t)layer * 384 * 128;
    const ushort_t* wtO = wtout + (size_t)layer * 128 * 128;
    const float* WinL  = Win  + (size_t)layer * 128 * 384;
    const float* WoutL = Wout + (size_t)layer * 128 * 128;
    const float* binL  = bin  + layer * 384;
    const float* boutL = bout + layer * 128;
    const float* lngL  = lng  + layer * 128;
    const float* lnbL  = lnb  + layer * 128;

    // ---- hoist x B-fragments (col n_mine), reused by all qkv tiles ----
    bf16x8 xf[4];
    {
      const float* xr = xsrc + (size_t)n_mine * 128 + 8 * lg;
#pragma unroll
      for (int kk = 0; kk < 4; ++kk) {
        const float4 a = *(const float4*)(xr + 32 * kk);
        const float4 c = *(const float4*)(xr + 32 * kk + 4);
        bf16x8 f;
        f[0] = (short)f2bf(a.x); f[1] = (short)f2bf(a.y);
        f[2] = (short)f2bf(a.z); f[3] = (short)f2bf(a.w);
        f[4] = (short)f2bf(c.x); f[5] = (short)f2bf(c.y);
        f[6] = (short)f2bf(c.z); f[7] = (short)f2bf(c.w);
        xf[kk] = f;
      }
    }

    // ---- pass 1: q (tiles 0..7) -> bufA, k (tiles 8..15) -> bufB ----
    float ssq = 0.f, ssk = 0.f;
    {
      bf16x8 awA[4], awB[4], nwA[4], nwB[4];
#pragma unroll
      for (int kk = 0; kk < 4; ++kk) {
        awA[kk] = wt_frag<WS>(wtI, WinL, lc,       8 * lg + 32 * kk, 384);
        awB[kk] = wt_frag<WS>(wtI, WinL, 128 + lc, 8 * lg + 32 * kk, 384);
      }
      for (int i = 0; i < 8; ++i) {
        if (i < 7) {
#pragma unroll
          for (int kk = 0; kk < 4; ++kk) {
            nwA[kk] = wt_frag<WS>(wtI, WinL, 16 * (i + 1) + lc,       8 * lg + 32 * kk, 384);
            nwB[kk] = wt_frag<WS>(wtI, WinL, 128 + 16 * (i + 1) + lc, 8 * lg + 32 * kk, 384);
          }
        }
        f32x4 aA = {0, 0, 0, 0}, aB = {0, 0, 0, 0};
#pragma unroll
        for (int kk = 0; kk < 4; ++kk) {
          aA = MFMA(awA[kk], xf[kk], aA);
          aB = MFMA(awB[kk], xf[kk], aB);
        }
        qkv_epi(bufA, i, aA, binL,       n_mine, lg, ssq);
        qkv_epi(bufB, i, aB, binL + 128, n_mine, lg, ssk);
#pragma unroll
        for (int kk = 0; kk < 4; ++kk) { awA[kk] = nwA[kk]; awB[kk] = nwB[kk]; }
      }
    }
    ssq += __shfl_xor(ssq, 16); ssq += __shfl_xor(ssq, 32);
    ssk += __shfl_xor(ssk, 16); ssk += __shfl_xor(ssk, 32);
    if (l < 16) { pQ[n_mine] = ssq; pK[n_mine] = ssk; }
    __syncthreads();   // B1: q,k complete + norm partials

    if (t < 128) {
      pQ[t] = 1.0f / fmaxf(sqrtf(pQ[t]), 1e-12f);
      fA[4 * t + 0] = (1.0f / fmaxf(sqrtf(pK[t]), 1e-12f)) * F_SCALING;
      fA[4 * t + 1] = sSW[t];
      fA[4 * t + 2] = 0.0f;
      fA[4 * t + 3] = sRX[t];
      fB[2 * t + 0] = sRY[t];
      fB[2 * t + 1] = sRZ[t];
    }
    // hoist q fragments (wave's own rows n_mine)
    bf16x8 qf[4];
#pragma unroll
    for (int kk = 0; kk < 4; ++kk)
      qf[kk] = *(const bf16x8*)(bufA + n_mine * ROWP + 8 * lg + 32 * kk);
    __syncthreads();   // B2: qf hoisted by all; factor tables ready; bufA free

    // ---- pass 2: v (tiles 16..23) -> bufA ----
    float ssv = 0.f;
    for (int i = 0; i < 4; ++i) {
      bf16x8 bwA[4], bwB[4];
#pragma unroll
      for (int kk = 0; kk < 4; ++kk) {
        bwA[kk] = wt_frag<WS>(wtI, WinL, 256 + 16 * i + lc, 8 * lg + 32 * kk, 384);
        bwB[kk] = wt_frag<WS>(wtI, WinL, 320 + 16 * i + lc, 8 * lg + 32 * kk, 384);
      }
      f32x4 aA = {0, 0, 0, 0}, aB = {0, 0, 0, 0};
#pragma unroll
      for (int kk = 0; kk < 4; ++kk) {
        aA = MFMA(bwA[kk], xf[kk], aA);
        aB = MFMA(bwB[kk], xf[kk], aB);
      }
      qkv_epi(bufA, i,     aA, binL + 256, n_mine, lg, ssv);
      qkv_epi(bufA, i + 4, aB, binL + 256, n_mine, lg, ssv);
    }
    ssv += __shfl_xor(ssv, 16); ssv += __shfl_xor(ssv, 32);
    if (l < 16) pV[n_mine] = ssv;

    // ---- S^T = k * q^T (reads bufB + qf), softmax prefactors in regs ----
    f32x4 sacc[8];
#pragma unroll
    for (int i = 0; i < 4; ++i) {
      bf16x8 kA[4], kB[4];
#pragma unroll
      for (int kk = 0; kk < 4; ++kk) {
        kA[kk] = *(const bf16x8*)(bufB + (16 * i + lc)       * ROWP + 8 * lg + 32 * kk);
        kB[kk] = *(const bf16x8*)(bufB + (16 * (i + 4) + lc) * ROWP + 8 * lg + 32 * kk);
      }
      f32x4 aA = {0, 0, 0, 0}, aB = {0, 0, 0, 0};
#pragma unroll
      for (int kk = 0; kk < 4; ++kk) {
        aA = MFMA(kA[kk], qf[kk], aA);
        aB = MFMA(kB[kk], qf[kk], aB);
      }
      sacc[i] = aA; sacc[i + 4] = aB;
    }
    {
      const float iqn = pQ[n_mine];
      const float swn = sSW[n_mine];
      const float rxn = sRX[n_mine], ryn = sRY[n_mine], rzn = sRZ[n_mine];
      float sum = 0.0f;
#pragma unroll
      for (int mt = 0; mt < 8; ++mt) {
#pragma unroll
        for (int r2 = 0; r2 < 4; ++r2) {
          const int m = 16 * mt + 4 * lg + r2;
          const float4 a4 = *(const float4*)&fA[4 * m];
          const float2 b2 = *(const float2*)&fB[2 * m];
          const float sws = swn * a4.y;
          const float lgt = (sacc[mt][r2] * iqn * a4.x + F_SHIFT) * sws - F_SHIFT;
          const float e = __expf(lgt);   // logits in [-20, 0.09]
          sum += e;
          const float ang = rxn * a4.w + ryn * b2.x + rzn * b2.y;
          sacc[mt][r2] = e * sws * ang;  // 1/|v| folded into VW^T instead
        }
      }
      sum += __shfl_xor(sum, 16); sum += __shfl_xor(sum, 32);
      const float fac = sMK[n_mine] / sum;
#pragma unroll
      for (int mt = 0; mt < 8; ++mt) {
#pragma unroll
        for (int r2 = 0; r2 < 4; ++r2) sacc[mt][r2] *= fac;
      }
    }
    __syncthreads();   // B3: v complete; all S reads of bufB done; pV written

    if (t < 128) sIV[t] = 1.0f / fmaxf(sqrtf(pV[t]), 1e-12f);
    // store P -> bufB (own rows)
#pragma unroll
    for (int mt = 0; mt < 8; ++mt) {
      *(ushort4*)(bufB + n_mine * ROWP + 16 * mt + 4 * lg) =
          pack4(sacc[mt][0], sacc[mt][1], sacc[mt][2], sacc[mt][3]);
    }
    // hoist v fragments (wave's own rows)
    bf16x8 vf[4];
#pragma unroll
    for (int kk = 0; kk < 4; ++kk)
      vf[kk] = *(const bf16x8*)(bufA + n_mine * ROWP + 8 * lg + 32 * kk);
    __syncthreads();   // B4: P stored, vf hoisted by all, sIV ready; bufA free

    // hoist P fragments (own rows; stored by self before B4)
    bf16x8 pf[4];
#pragma unroll
    for (int kk = 0; kk < 4; ++kk)
      pf[kk] = *(const bf16x8*)(bufB + n_mine * ROWP + 8 * lg + 32 * kk);

    // ---- VW^T = (v @ W_out)^T * iv  -> bufA ----
    {
      const float4 ivm = *(const float4*)&sIV[16 * w + 4 * lg];
#pragma unroll
      for (int i = 0; i < 4; ++i) {
        bf16x8 bwA[4], bwB[4];
#pragma unroll
        for (int kk = 0; kk < 4; ++kk) {
          bwA[kk] = wt_frag<WS>(wtO, WoutL, 16 * i + lc,       8 * lg + 32 * kk, 128);
          bwB[kk] = wt_frag<WS>(wtO, WoutL, 16 * (i + 4) + lc, 8 * lg + 32 * kk, 128);
        }
        f32x4 aA = {0, 0, 0, 0}, aB = {0, 0, 0, 0};
#pragma unroll
        for (int kk = 0; kk < 4; ++kk) {
          aA = MFMA(vf[kk], bwA[kk], aA);
          aB = MFMA(vf[kk], bwB[kk], aB);
        }
        *(ushort4*)(bufA + (16 * i + lc) * ROWP + 16 * w + 4 * lg) =
            pack4(aA[0] * ivm.x, aA[1] * ivm.y, aA[2] * ivm.z, aA[3] * ivm.w);
        *(ushort4*)(bufA + (16 * (i + 4) + lc) * ROWP + 16 * w + 4 * lg) =
            pack4(aB[0] * ivm.x, aB[1] * ivm.y, aB[2] * ivm.z, aB[3] * ivm.w);
      }
    }
    __syncthreads();   // B5: VW^T complete

    // ---- out = P @ VW ; wave owns rows 16w..16w+15, all 8 e-tiles ----
    f32x4 oacc[8];
#pragma unroll
    for (int i = 0; i < 4; ++i) {
      bf16x8 bA[4], bB[4];
#pragma unroll
      for (int kk = 0; kk < 4; ++kk) {
        bA[kk] = *(const bf16x8*)(bufA + (16 * i + lc)       * ROWP + 8 * lg + 32 * kk);
        bB[kk] = *(const bf16x8*)(bufA + (16 * (i + 4) + lc) * ROWP + 8 * lg + 32 * kk);
      }
      f32x4 aA = {0, 0, 0, 0}, aB = {0, 0, 0, 0};
#pragma unroll
      for (int kk = 0; kk < 4; ++kk) {
        aA = MFMA(pf[kk], bA[kk], aA);
        aB = MFMA(pf[kk], bB[kk], aB);
      }
      oacc[i] = aA; oacc[i + 4] = aB;
    }

    // ---- epilogue: +b_out +residual(fp32), LayerNorm, write x' ----
    {
      float bo8[8], g8[8], be8[8];
#pragma unroll
      for (int ct = 0; ct < 8; ++ct) {
        const int e = 16 * ct + lc;
        bo8[ct] = boutL[e]; g8[ct] = lngL[e]; be8[ct] = lnbL[e];
      }
#pragma unroll
      for (int r2 = 0; r2 < 4; ++r2) {
        const int n = 16 * w + 4 * lg + r2;
        const float* xr = xsrc + (size_t)n * 128;
        float vals[8];
        float s1 = 0.0f, s2 = 0.0f;
#pragma unroll
        for (int ct = 0; ct < 8; ++ct) {
          const float v = oacc[ct][r2] + bo8[ct] + xr[16 * ct + lc];
          vals[ct] = v; s1 += v; s2 += v * v;
        }
        s1 += __shfl_xor(s1, 1); s1 += __shfl_xor(s1, 2);
        s1 += __shfl_xor(s1, 4); s1 += __shfl_xor(s1, 8);
        s2 += __shfl_xor(s2, 1); s2 += __shfl_xor(s2, 2);
        s2 += __shfl_xor(s2, 4); s2 += __shfl_xor(s2, 8);
        const float mu = s1 * (1.0f / 128.0f);
        const float rs = rsqrtf(s2 * (1.0f / 128.0f) - mu * mu + F_LNEPS);
        float* orow = xout + bb + (size_t)n * 128;
#pragma unroll
        for (int ct = 0; ct < 8; ++ct)
          orow[16 * ct + lc] = (vals[ct] - mu) * rs * g8[ct] + be8[ct];
      }
    }
    __syncthreads();   // B6: layer boundary (buffers reused; xout -> next xsrc)
  }
}

extern "C" void kernel_launch(void* const* d_in, const int* in_sizes, int n_in,
                              void* d_out, int out_size, void* d_ws, size_t ws_size,
                              hipStream_t stream) {
  const float* G    = (const float*)d_in[0];
  const int*   msk  = (const int*)d_in[1];
  const float* r3   = (const float*)d_in[2];
  const float* swg  = (const float*)d_in[3];
  const float* Win  = (const float*)d_in[4];
  const float* bin  = (const float*)d_in[5];
  const float* Wout = (const float*)d_in[6];
  const float* bout = (const float*)d_in[7];
  const float* lng  = (const float*)d_in[8];
  const float* lnb  = (const float*)d_in[9];
  float* xout = (float*)d_out;

  const int B = in_sizes[0] / (128 * 128);
  const bool ws_ok = ws_size >= (WTI_ELEMS + WTO_ELEMS) * sizeof(ushort_t);
  ushort_t* wtI = (ushort_t*)d_ws;
  ushort_t* wtO = wtI + WTI_ELEMS;

  if (ws_ok) {
    prep_weights<<<dim3(384), dim3(256), 0, stream>>>(Win, Wout, wtI, wtO);
    hipFuncSetAttribute(reinterpret_cast<const void*>(ngatt_mfma<true>),
                        hipFuncAttributeMaxDynamicSharedMemorySize, LDS_BYTES);
    ngatt_mfma<true><<<dim3(B), dim3(512), LDS_BYTES, stream>>>(
        G, msk, r3, swg, Win, bin, Wout, bout, lng, lnb, wtI, wtO, xout);
  } else {
    hipFuncSetAttribute(reinterpret_cast<const void*>(ngatt_mfma<false>),
                        hipFuncAttributeMaxDynamicSharedMemorySize, LDS_BYTES);
    ngatt_mfma<false><<<dim3(B), dim3(512), LDS_BYTES, stream>>>(
        G, msk, r3, swg, Win, bin, Wout, bout, lng, lnb, nullptr, nullptr, xout);
  }
}